// Round 1
// baseline (1154.385 us; speedup 1.0000x reference)
//
#include <hip/hip_runtime.h>

// ---------------------------------------------------------------------------
// ConstraintLoss:
//   values = sigmoid(pred)                                  [n_vars]
//   ax = segment_sum(coeff * values[var_idx], constr_idx)   [n_constrs]
//   viol[c] = sense==1 ? relu(ax-b) : sense==2 ? relu(b-ax) : sense==3 ? |ax-b| : 0
//   out = mean(viol)
// ---------------------------------------------------------------------------

__global__ void sigmoid_kernel(const float* __restrict__ pred,
                               float* __restrict__ values, int n) {
    int i = blockIdx.x * blockDim.x + threadIdx.x;
    int stride = gridDim.x * blockDim.x;
    int n4 = n >> 2;
    const float4* p4 = (const float4*)pred;
    float4* v4 = (float4*)values;
    for (int j = i; j < n4; j += stride) {
        float4 p = p4[j];
        float4 v;
        v.x = 1.0f / (1.0f + __expf(-p.x));
        v.y = 1.0f / (1.0f + __expf(-p.y));
        v.z = 1.0f / (1.0f + __expf(-p.z));
        v.w = 1.0f / (1.0f + __expf(-p.w));
        v4[j] = v;
    }
    // tail
    for (int j = (n4 << 2) + i; j < n; j += stride)
        values[j] = 1.0f / (1.0f + __expf(-pred[j]));
}

__global__ void scatter_kernel(const int* __restrict__ cidx,
                               const int* __restrict__ vidx,
                               const float* __restrict__ coeff,
                               const float* __restrict__ values,
                               float* __restrict__ ax, int nnz) {
    int i = blockIdx.x * blockDim.x + threadIdx.x;
    int stride = gridDim.x * blockDim.x;
    int n4 = nnz >> 2;
    const int4* c4 = (const int4*)cidx;
    const int4* v4 = (const int4*)vidx;
    const float4* w4 = (const float4*)coeff;
    for (int j = i; j < n4; j += stride) {
        int4 c = c4[j];
        int4 v = v4[j];
        float4 w = w4[j];
        atomicAdd(&ax[c.x], w.x * values[v.x]);
        atomicAdd(&ax[c.y], w.y * values[v.y]);
        atomicAdd(&ax[c.z], w.z * values[v.z]);
        atomicAdd(&ax[c.w], w.w * values[v.w]);
    }
    for (int j = (n4 << 2) + i; j < nnz; j += stride)
        atomicAdd(&ax[cidx[j]], coeff[j] * values[vidx[j]]);
}

__global__ void violation_reduce_kernel(const float* __restrict__ ax,
                                        const float* __restrict__ rhs,
                                        const int* __restrict__ sense,
                                        float* __restrict__ out,
                                        int n, float inv_n) {
    int i = blockIdx.x * blockDim.x + threadIdx.x;
    int stride = gridDim.x * blockDim.x;
    float acc = 0.0f;
    int n4 = n >> 2;
    const float4* a4 = (const float4*)ax;
    const float4* r4 = (const float4*)rhs;
    const int4* s4 = (const int4*)sense;
    for (int j = i; j < n4; j += stride) {
        float4 a = a4[j];
        float4 r = r4[j];
        int4 s = s4[j];
        float d;
        d = a.x - r.x;
        acc += (s.x == 1) ? fmaxf(d, 0.0f) : (s.x == 2) ? fmaxf(-d, 0.0f) : (s.x == 3) ? fabsf(d) : 0.0f;
        d = a.y - r.y;
        acc += (s.y == 1) ? fmaxf(d, 0.0f) : (s.y == 2) ? fmaxf(-d, 0.0f) : (s.y == 3) ? fabsf(d) : 0.0f;
        d = a.z - r.z;
        acc += (s.z == 1) ? fmaxf(d, 0.0f) : (s.z == 2) ? fmaxf(-d, 0.0f) : (s.z == 3) ? fabsf(d) : 0.0f;
        d = a.w - r.w;
        acc += (s.w == 1) ? fmaxf(d, 0.0f) : (s.w == 2) ? fmaxf(-d, 0.0f) : (s.w == 3) ? fabsf(d) : 0.0f;
    }
    for (int j = (n4 << 2) + i; j < n; j += stride) {
        float d = ax[j] - rhs[j];
        int s = sense[j];
        acc += (s == 1) ? fmaxf(d, 0.0f) : (s == 2) ? fmaxf(-d, 0.0f) : (s == 3) ? fabsf(d) : 0.0f;
    }

    // wave-64 reduction
    for (int off = 32; off > 0; off >>= 1)
        acc += __shfl_down(acc, off, 64);

    __shared__ float lds[8];  // up to 512 threads / 64
    int lane = threadIdx.x & 63;
    int wave = threadIdx.x >> 6;
    if (lane == 0) lds[wave] = acc;
    __syncthreads();
    if (wave == 0) {
        int nwaves = blockDim.x >> 6;
        float b = (lane < nwaves) ? lds[lane] : 0.0f;
        for (int off = 4; off > 0; off >>= 1)
            b += __shfl_down(b, off, 64);
        if (lane == 0) atomicAdd(out, b * inv_n);
    }
}

extern "C" void kernel_launch(void* const* d_in, const int* in_sizes, int n_in,
                              void* d_out, int out_size, void* d_ws, size_t ws_size,
                              hipStream_t stream) {
    const float* pred  = (const float*)d_in[0];
    const int*   cidx  = (const int*)d_in[1];
    const int*   vidx  = (const int*)d_in[2];
    const float* coeff = (const float*)d_in[3];
    const float* rhs   = (const float*)d_in[4];
    const int*   sense = (const int*)d_in[5];

    const int n_vars    = in_sizes[0];
    const int nnz       = in_sizes[1];
    const int n_constrs = in_sizes[4];

    float* values = (float*)d_ws;                 // n_vars floats
    float* ax     = values + n_vars;              // n_constrs floats

    // zero the accumulator buffer and the output (both re-poisoned each call)
    hipMemsetAsync(ax, 0, (size_t)n_constrs * sizeof(float), stream);
    hipMemsetAsync(d_out, 0, sizeof(float), stream);

    {
        int threads = 256;
        int work = n_vars >> 2;
        int blocks = (work + threads - 1) / threads;
        if (blocks > 4096) blocks = 4096;
        sigmoid_kernel<<<blocks, threads, 0, stream>>>(pred, values, n_vars);
    }
    {
        int threads = 256;
        int work = nnz >> 2;
        int blocks = (work + threads - 1) / threads;
        if (blocks > 8192) blocks = 8192;
        scatter_kernel<<<blocks, threads, 0, stream>>>(cidx, vidx, coeff, values, ax, nnz);
    }
    {
        int threads = 256;
        int work = n_constrs >> 2;
        int blocks = (work + threads - 1) / threads;
        if (blocks > 4096) blocks = 4096;
        violation_reduce_kernel<<<blocks, threads, 0, stream>>>(
            ax, rhs, sense, (float*)d_out, n_constrs, 1.0f / (float)n_constrs);
    }
}